// Round 1
// baseline (1010.134 us; speedup 1.0000x reference)
//
#include <hip/hip_runtime.h>
#include <hip/hip_bf16.h>

// Problem constants (from reference)
#define NN 50000
#define NE 800000
#define DD 256
#define OO 32

// ---------------------------------------------------------------------------
// CSR build: count, scan (single block), scatter
// ---------------------------------------------------------------------------
__global__ void count_kernel(const int* __restrict__ row, int* __restrict__ cnt, int E) {
    int e = blockIdx.x * blockDim.x + threadIdx.x;
    if (e < E) atomicAdd(&cnt[row[e]], 1);
}

__global__ __launch_bounds__(1024) void scan_kernel(const int* __restrict__ cnt,
                                                    int* __restrict__ row_ptr,
                                                    int* __restrict__ cursor,
                                                    float* __restrict__ dinv,
                                                    int N, int E) {
    __shared__ int s[1024];
    int t = threadIdx.x;
    int per = (N + 1023) / 1024;
    int lo = t * per, hi = min(lo + per, N);
    int sum = 0;
    for (int i = lo; i < hi; ++i) sum += cnt[i];
    s[t] = sum;
    __syncthreads();
    // Hillis-Steele inclusive scan (read-all before write-all via barriers)
    for (int off = 1; off < 1024; off <<= 1) {
        int other = (t >= off) ? s[t - off] : 0;
        __syncthreads();
        s[t] += other;
        __syncthreads();
    }
    int run = s[t] - sum;  // exclusive prefix of this thread's chunk
    for (int i = lo; i < hi; ++i) {
        row_ptr[i] = run;
        cursor[i] = run;
        int c = cnt[i];
        dinv[i] = rsqrtf((float)(c + 1));  // +1 self-loop; deg >= 1 always
        run += c;
    }
    if (t == 0) row_ptr[N] = E;
}

__global__ void scatter_kernel(const int* __restrict__ row, const int* __restrict__ col,
                               int* __restrict__ cursor, int* __restrict__ csr_col, int E) {
    int e = blockIdx.x * blockDim.x + threadIdx.x;
    if (e < E) {
        int p = atomicAdd(&cursor[row[e]], 1);
        csr_col[p] = col[e];
    }
}

// ---------------------------------------------------------------------------
// fp32 GEMM: C[M x 256] = A[M x 256] @ W[256 x 256] + bias
// 128x128 tile, BK=8, 256 threads, 8x8 acc per thread
// ---------------------------------------------------------------------------
__global__ __launch_bounds__(256) void gemm_bias_256(const float* __restrict__ A,
                                                     const float* __restrict__ W,
                                                     const float* __restrict__ bias,
                                                     float* __restrict__ C, int M) {
    const int K = 256, NC = 256;
    __shared__ float As[8][128];
    __shared__ float Bs[8][128];
    int tid = threadIdx.x;
    int rowBase = blockIdx.x * 128;
    int colBase = blockIdx.y * 128;
    int tx = tid & 15, ty = tid >> 4;

    float acc[8][8];
#pragma unroll
    for (int i = 0; i < 8; ++i)
#pragma unroll
        for (int j = 0; j < 8; ++j) acc[i][j] = 0.f;

    int lrow = tid >> 1, lk4 = (tid & 1) * 4;   // A: 128 rows x 8 k, float4 per thread
    int bk = tid >> 5, bj4 = (tid & 31) * 4;    // B: 8 k x 128 cols, float4 per thread

    for (int k0 = 0; k0 < K; k0 += 8) {
        float4 av;
        int gr = rowBase + lrow;
        if (gr < M) av = *(const float4*)(A + (size_t)gr * K + k0 + lk4);
        else av = make_float4(0.f, 0.f, 0.f, 0.f);
        float4 bv = *(const float4*)(W + (size_t)(k0 + bk) * NC + colBase + bj4);
        __syncthreads();  // previous iteration's LDS reads done
        As[lk4 + 0][lrow] = av.x;
        As[lk4 + 1][lrow] = av.y;
        As[lk4 + 2][lrow] = av.z;
        As[lk4 + 3][lrow] = av.w;
        *(float4*)(&Bs[bk][bj4]) = bv;
        __syncthreads();
#pragma unroll
        for (int kk = 0; kk < 8; ++kk) {
            float a[8], b[8];
#pragma unroll
            for (int i = 0; i < 8; ++i) a[i] = As[kk][ty * 8 + i];
#pragma unroll
            for (int j = 0; j < 8; ++j) b[j] = Bs[kk][tx * 8 + j];
#pragma unroll
            for (int i = 0; i < 8; ++i)
#pragma unroll
                for (int j = 0; j < 8; ++j) acc[i][j] = fmaf(a[i], b[j], acc[i][j]);
        }
    }
#pragma unroll
    for (int i = 0; i < 8; ++i) {
        int r = rowBase + ty * 8 + i;
        if (r >= M) continue;
#pragma unroll
        for (int j = 0; j < 8; j += 4) {
            int c = colBase + tx * 8 + j;
            float4 o;
            o.x = acc[i][j + 0] + bias[c + 0];
            o.y = acc[i][j + 1] + bias[c + 1];
            o.z = acc[i][j + 2] + bias[c + 2];
            o.w = acc[i][j + 3] + bias[c + 3];
            *(float4*)(C + (size_t)r * NC + c) = o;
        }
    }
}

// ---------------------------------------------------------------------------
// Fused: agg (APPNP step) + residual + L2-normalize + ReLU
// out[v] = relu( l2norm( h0[v] + 0.5*dinv[v]*(dinv[v]*nb[v] + sum_c dinv[c]*nb[c]) + 0.5*nb[v] ) )
// One block (256 threads) per node; thread d handles feature d.
// Writes in-place over h0 are safe (h0 only read at [v] by block v).
// ---------------------------------------------------------------------------
__global__ __launch_bounds__(256) void agg_norm_relu(const float* __restrict__ h0,
                                                     const float* __restrict__ nb,
                                                     const float* __restrict__ dinv,
                                                     const int* __restrict__ row_ptr,
                                                     const int* __restrict__ csr_col,
                                                     float* __restrict__ outp) {
    __shared__ int s_col[256];
    __shared__ float s_dc[256];
    __shared__ float red[256];
    int v = blockIdx.x;
    int d = threadIdx.x;
    float dv = dinv[v];
    float nbv = nb[(size_t)v * DD + d];
    float acc = dv * nbv;  // self-loop term (before outer dv factor)
    int start = row_ptr[v], end = row_ptr[v + 1];
    for (int base = start; base < end; base += 256) {
        int m = min(256, end - base);
        __syncthreads();
        if (d < m) {
            int c = csr_col[base + d];
            s_col[d] = c;
            s_dc[d] = dinv[c];
        }
        __syncthreads();
        for (int j = 0; j < m; ++j) {
            acc += s_dc[j] * nb[(size_t)s_col[j] * DD + d];
        }
    }
    float val = h0[(size_t)v * DD + d] + 0.5f * (dv * acc) + 0.5f * nbv;
    red[d] = val * val;
    __syncthreads();
    for (int s = 128; s > 0; s >>= 1) {
        if (d < s) red[d] += red[d + s];
        __syncthreads();
    }
    float nrm = sqrtf(red[0]);
    val = val / fmaxf(nrm, 1e-12f);
    val = fmaxf(val, 0.f);
    outp[(size_t)v * DD + d] = val;
}

// ---------------------------------------------------------------------------
// Final projection: out[M x 32] = A[M x 256] @ W2[256 x 32] + b2
// Block: 256 threads = 8 rows x 32 cols; W2 staged in LDS
// ---------------------------------------------------------------------------
__global__ __launch_bounds__(256) void gemm_final(const float* __restrict__ A,
                                                  const float* __restrict__ W2,
                                                  const float* __restrict__ b2,
                                                  float* __restrict__ out, int M) {
    __shared__ float Ws[256 * 32];
    __shared__ float Arow[8][256];
    int tid = threadIdx.x;
    for (int i = tid; i < 256 * 32; i += 256) Ws[i] = W2[i];
    int rowBase = blockIdx.x * 8;
    for (int i = tid; i < 8 * 256; i += 256) {
        int rr = rowBase + (i >> 8);
        Arow[i >> 8][i & 255] = (rr < M) ? A[(size_t)rr * 256 + (i & 255)] : 0.f;
    }
    __syncthreads();
    int r = tid >> 5;
    int j = tid & 31;
    float acc = 0.f;
#pragma unroll 8
    for (int k = 0; k < 256; ++k) acc = fmaf(Arow[r][k], Ws[k * 32 + j], acc);
    int gr = rowBase + r;
    if (gr < M) out[(size_t)gr * 32 + j] = acc + b2[j];
}

// ---------------------------------------------------------------------------
extern "C" void kernel_launch(void* const* d_in, const int* in_sizes, int n_in,
                              void* d_out, int out_size, void* d_ws, size_t ws_size,
                              hipStream_t stream) {
    const float* x   = (const float*)d_in[0];
    const int* edge  = (const int*)d_in[1];
    const float* W0  = (const float*)d_in[2];
    const float* b0  = (const float*)d_in[3];
    const float* Wn0 = (const float*)d_in[4];
    const float* bn0 = (const float*)d_in[5];
    const float* W1  = (const float*)d_in[6];
    const float* b1  = (const float*)d_in[7];
    const float* Wn1 = (const float*)d_in[8];
    const float* bn1 = (const float*)d_in[9];
    const float* W2  = (const float*)d_in[10];
    const float* b2  = (const float*)d_in[11];
    float* out = (float*)d_out;

    const int N = NN, E = NE, D = DD;
    const int* row = edge;
    const int* col = edge + E;

    // Workspace layout (~106.4 MB)
    float* A = (float*)d_ws;                       // N*D floats
    float* B = A + (size_t)N * D;                  // N*D floats
    int* cnt = (int*)(B + (size_t)N * D);          // N
    int* row_ptr = cnt + N;                        // N+1
    int* cursor = row_ptr + (N + 1);               // N
    float* dinv = (float*)(cursor + N);            // N
    int* csr_col = (int*)(dinv + N);               // E

    // CSR build (edge_index is re-restored by harness each call)
    hipMemsetAsync(cnt, 0, (size_t)N * sizeof(int), stream);
    int eb = (E + 255) / 256;
    count_kernel<<<eb, 256, 0, stream>>>(row, cnt, E);
    scan_kernel<<<1, 1024, 0, stream>>>(cnt, row_ptr, cursor, dinv, N, E);
    scatter_kernel<<<eb, 256, 0, stream>>>(row, col, cursor, csr_col, E);

    dim3 g1((N + 127) / 128, 2);
    // Layer 1: h0 = x@W0+b0 -> A ; nb = A@Wn0+bn0 -> B ; agg(A,B) -> A
    gemm_bias_256<<<g1, 256, 0, stream>>>(x, W0, b0, A, N);
    gemm_bias_256<<<g1, 256, 0, stream>>>(A, Wn0, bn0, B, N);
    agg_norm_relu<<<N, 256, 0, stream>>>(A, B, dinv, row_ptr, csr_col, A);
    // Layer 2: h0 = A@W1+b1 -> B ; nb = B@Wn1+bn1 -> A ; agg(B,A) -> B
    gemm_bias_256<<<g1, 256, 0, stream>>>(A, W1, b1, B, N);
    gemm_bias_256<<<g1, 256, 0, stream>>>(B, Wn1, bn1, A, N);
    agg_norm_relu<<<N, 256, 0, stream>>>(B, A, dinv, row_ptr, csr_col, B);
    // Final: out = B@W2+b2
    gemm_final<<<(N + 7) / 8, 256, 0, stream>>>(B, W2, b2, out, N);
}

// Round 2
// 463.289 us; speedup vs baseline: 2.1804x; 2.1804x over previous
//
#include <hip/hip_runtime.h>
#include <hip/hip_bf16.h>

#define NN 50000
#define NE 800000
#define DD 256
#define OO 32

typedef __attribute__((ext_vector_type(8))) short short8;
typedef __attribute__((ext_vector_type(4))) float float4v;

#define AS1 __attribute__((address_space(1)))
#define AS3 __attribute__((address_space(3)))

__device__ __forceinline__ float b2f(unsigned short u) {
    union { unsigned int i; float f; } x;
    x.i = ((unsigned int)u) << 16;
    return x.f;
}
__device__ __forceinline__ unsigned short f2b(float f) {
    union { float f; unsigned int i; } x;
    x.f = f;
    unsigned int r = x.i + 0x7FFFu + ((x.i >> 16) & 1u);  // RNE
    return (unsigned short)(r >> 16);
}

// ---------------------------------------------------------------------------
// CSR build
// ---------------------------------------------------------------------------
__global__ void count_kernel(const int* __restrict__ row, int* __restrict__ cnt, int E) {
    int e = blockIdx.x * blockDim.x + threadIdx.x;
    if (e < E) atomicAdd(&cnt[row[e]], 1);
}

__global__ __launch_bounds__(256) void block_sums(const int* __restrict__ cnt,
                                                  int* __restrict__ bsum, int N) {
    __shared__ int s[256];
    int idx = blockIdx.x * 256 + threadIdx.x;
    s[threadIdx.x] = (idx < N) ? cnt[idx] : 0;
    __syncthreads();
    for (int o = 128; o > 0; o >>= 1) {
        if (threadIdx.x < o) s[threadIdx.x] += s[threadIdx.x + o];
        __syncthreads();
    }
    if (threadIdx.x == 0) bsum[blockIdx.x] = s[0];
}

__global__ __launch_bounds__(256) void scan_bsums(const int* __restrict__ bsum,
                                                  int* __restrict__ bpre, int nb) {
    __shared__ int s[256];
    int t = threadIdx.x;
    int v0 = (t < nb) ? bsum[t] : 0;
    s[t] = v0;
    __syncthreads();
    for (int o = 1; o < 256; o <<= 1) {
        int v = (t >= o) ? s[t - o] : 0;
        __syncthreads();
        s[t] += v;
        __syncthreads();
    }
    if (t < nb) bpre[t] = s[t] - v0;  // exclusive prefix
}

__global__ __launch_bounds__(256) void fill_rowptr(const int* __restrict__ cnt,
                                                   const int* __restrict__ bpre,
                                                   int* __restrict__ row_ptr,
                                                   int* __restrict__ cursor,
                                                   float* __restrict__ dinv, int N, int E) {
    __shared__ int s[256];
    int t = threadIdx.x;
    int idx = blockIdx.x * 256 + t;
    int c = (idx < N) ? cnt[idx] : 0;
    s[t] = c;
    __syncthreads();
    for (int o = 1; o < 256; o <<= 1) {
        int v = (t >= o) ? s[t - o] : 0;
        __syncthreads();
        s[t] += v;
        __syncthreads();
    }
    int excl = bpre[blockIdx.x] + s[t] - c;
    if (idx < N) {
        row_ptr[idx] = excl;
        cursor[idx] = excl;
        dinv[idx] = rsqrtf((float)(c + 1));  // +1 self-loop
    }
    if (idx == N) row_ptr[N] = E;
}

__global__ void scatter_kernel(const int* __restrict__ row, const int* __restrict__ col,
                               int* __restrict__ cursor, int* __restrict__ csr_col, int E) {
    int e = blockIdx.x * blockDim.x + threadIdx.x;
    if (e < E) {
        int p = atomicAdd(&cursor[row[e]], 1);
        csr_col[p] = col[e];
    }
}

// ---------------------------------------------------------------------------
// fp32 -> bf16 casts
// ---------------------------------------------------------------------------
__global__ __launch_bounds__(256) void cast_x_kernel(const float* __restrict__ x,
                                                     unsigned short* __restrict__ xb, int n4) {
    int i = blockIdx.x * 256 + threadIdx.x;
    if (i < n4) {
        float4 v = ((const float4*)x)[i];
        ushort4 o;
        o.x = f2b(v.x); o.y = f2b(v.y); o.z = f2b(v.z); o.w = f2b(v.w);
        ((ushort4*)xb)[i] = o;
    }
}

// Wt[n][k] = bf16(W[k][n]); one block per output row n, 256 threads over k
__global__ __launch_bounds__(256) void cast_wt_kernel(const float* __restrict__ W,
                                                      unsigned short* __restrict__ Wt, int Ncol) {
    int n = blockIdx.x;
    int k = threadIdx.x;
    Wt[n * 256 + k] = f2b(W[k * Ncol + n]);
}

// ---------------------------------------------------------------------------
// bf16 MFMA GEMM: C[M x 256](bf16) = A[M x 256](bf16) @ W(bf16, pre-transposed
// Wt[n][k]) + bias(fp32). m97 structure: 128x128 tile, BK=32, global_load_lds.
// ---------------------------------------------------------------------------
__global__ __launch_bounds__(256) void gemm_mfma(const unsigned short* __restrict__ A,
                                                 const unsigned short* __restrict__ Wt,
                                                 const float* __restrict__ bias,
                                                 unsigned short* __restrict__ C, int M) {
    __shared__ unsigned short Als[128 * 32];
    __shared__ unsigned short Bls[128 * 32];
    int tid = threadIdx.x;
    int lane = tid & 63, wave = tid >> 6;
    int rowBase = blockIdx.x * 128, colBase = blockIdx.y * 128;

    float4v acc[4][4];
#pragma unroll
    for (int i = 0; i < 4; ++i)
#pragma unroll
        for (int j = 0; j < 4; ++j) acc[i][j] = (float4v){0.f, 0.f, 0.f, 0.f};

    int wm = (wave & 1) * 64, wn = (wave >> 1) * 64;
    int sRow = wave * 32 + (lane >> 2);  // staging row within tile (call0)
    int sK = (lane & 3) * 8;             // ushort offset within 32-wide k row
    int fr = lane & 15, fk = (lane >> 4) * 8;

    for (int k0 = 0; k0 < 256; k0 += 32) {
        int r0 = rowBase + sRow;       if (r0 >= M) r0 = M - 1;
        int r1 = rowBase + sRow + 16;  if (r1 >= M) r1 = M - 1;
        __builtin_amdgcn_global_load_lds((const AS1 void*)(A + (size_t)r0 * 256 + k0 + sK),
                                         (AS3 void*)&Als[(wave * 32) * 32], 16, 0, 0);
        __builtin_amdgcn_global_load_lds((const AS1 void*)(A + (size_t)r1 * 256 + k0 + sK),
                                         (AS3 void*)&Als[(wave * 32 + 16) * 32], 16, 0, 0);
        __builtin_amdgcn_global_load_lds((const AS1 void*)(Wt + (size_t)(colBase + sRow) * 256 + k0 + sK),
                                         (AS3 void*)&Bls[(wave * 32) * 32], 16, 0, 0);
        __builtin_amdgcn_global_load_lds((const AS1 void*)(Wt + (size_t)(colBase + sRow + 16) * 256 + k0 + sK),
                                         (AS3 void*)&Bls[(wave * 32 + 16) * 32], 16, 0, 0);
        __syncthreads();

        short8 af[4], bfr[4];
#pragma unroll
        for (int i = 0; i < 4; ++i)
            af[i] = *(const short8*)&Als[(wm + i * 16 + fr) * 32 + fk];
#pragma unroll
        for (int j = 0; j < 4; ++j)
            bfr[j] = *(const short8*)&Bls[(wn + j * 16 + fr) * 32 + fk];
#pragma unroll
        for (int i = 0; i < 4; ++i)
#pragma unroll
            for (int j = 0; j < 4; ++j)
                acc[i][j] = __builtin_amdgcn_mfma_f32_16x16x32_bf16(af[i], bfr[j], acc[i][j], 0, 0, 0);
        __syncthreads();
    }

    // epilogue: C/D layout col=lane&15, row=(lane>>4)*4+reg
    int cr = (lane >> 4) * 4, cc = lane & 15;
#pragma unroll
    for (int i = 0; i < 4; ++i) {
#pragma unroll
        for (int j = 0; j < 4; ++j) {
            int colg = colBase + wn + j * 16 + cc;
            float bv = bias[colg];
#pragma unroll
            for (int r = 0; r < 4; ++r) {
                int rowg = rowBase + wm + i * 16 + cr + r;
                if (rowg < M) C[(size_t)rowg * 256 + colg] = f2b(acc[i][j][r] + bv);
            }
        }
    }
}

// ---------------------------------------------------------------------------
// Fused APPNP agg + residual + L2-norm + ReLU. One WAVE per node.
// Lane handles 4 features (ushort4 = 8B per gather). acc in fp32.
// out[v] = relu(l2norm(h0[v] + 0.5*dv*(dv*nb[v] + sum_c dc*nb[c]) + 0.5*nb[v]))
// ---------------------------------------------------------------------------
__global__ __launch_bounds__(256) void agg_norm_relu(const unsigned short* __restrict__ h0,
                                                     const unsigned short* __restrict__ nb,
                                                     const float* __restrict__ dinv,
                                                     const int* __restrict__ row_ptr,
                                                     const int* __restrict__ csr_col,
                                                     unsigned short* __restrict__ outp) {
    int wave = threadIdx.x >> 6, lane = threadIdx.x & 63;
    int v = blockIdx.x * 4 + wave;
    float dv = dinv[v];
    int base = v * 256 + lane * 4;
    ushort4 nbu = *(const ushort4*)(nb + base);
    float nbv0 = b2f(nbu.x), nbv1 = b2f(nbu.y), nbv2 = b2f(nbu.z), nbv3 = b2f(nbu.w);
    float a0 = dv * nbv0, a1 = dv * nbv1, a2 = dv * nbv2, a3 = dv * nbv3;

    int s = row_ptr[v], e = row_ptr[v + 1];
    for (int b0 = s; b0 < e; b0 += 64) {
        int m = e - b0;
        if (m > 64) m = 64;
        int c = 0;
        float dc = 0.f;
        if (lane < m) { c = csr_col[b0 + lane]; dc = dinv[c]; }
        for (int j = 0; j < m; ++j) {
            int cj = __shfl(c, j);
            float dcj = __shfl(dc, j);
            ushort4 u = *(const ushort4*)(nb + cj * 256 + lane * 4);
            a0 = fmaf(dcj, b2f(u.x), a0);
            a1 = fmaf(dcj, b2f(u.y), a1);
            a2 = fmaf(dcj, b2f(u.z), a2);
            a3 = fmaf(dcj, b2f(u.w), a3);
        }
    }
    ushort4 hu = *(const ushort4*)(h0 + base);
    float h0v0 = b2f(hu.x), h0v1 = b2f(hu.y), h0v2 = b2f(hu.z), h0v3 = b2f(hu.w);
    float v0 = h0v0 + 0.5f * dv * a0 + 0.5f * nbv0;
    float v1 = h0v1 + 0.5f * dv * a1 + 0.5f * nbv1;
    float v2 = h0v2 + 0.5f * dv * a2 + 0.5f * nbv2;
    float v3 = h0v3 + 0.5f * dv * a3 + 0.5f * nbv3;
    float ss = v0 * v0 + v1 * v1 + v2 * v2 + v3 * v3;
#pragma unroll
    for (int o = 32; o > 0; o >>= 1) ss += __shfl_xor(ss, o);
    float inv = 1.0f / fmaxf(sqrtf(ss), 1e-12f);
    ushort4 o;
    o.x = f2b(fmaxf(v0 * inv, 0.f));
    o.y = f2b(fmaxf(v1 * inv, 0.f));
    o.z = f2b(fmaxf(v2 * inv, 0.f));
    o.w = f2b(fmaxf(v3 * inv, 0.f));
    *(ushort4*)(outp + base) = o;
}

// ---------------------------------------------------------------------------
// Final projection (MFMA): out[M x 32](fp32) = A[M x 256](bf16) @ W2 + b2
// Wt2[n][k] pre-transposed bf16 (32 x 256). 128-row tile, wave = 32 rows.
// ---------------------------------------------------------------------------
__global__ __launch_bounds__(256) void gemm_final_mfma(const unsigned short* __restrict__ A,
                                                       const unsigned short* __restrict__ Wt2,
                                                       const float* __restrict__ b2,
                                                       float* __restrict__ out, int M) {
    __shared__ unsigned short Als[128 * 32];
    __shared__ unsigned short Bls[32 * 32];
    int tid = threadIdx.x;
    int lane = tid & 63, wave = tid >> 6;
    int rowBase = blockIdx.x * 128;

    float4v acc[2][2];
#pragma unroll
    for (int i = 0; i < 2; ++i)
#pragma unroll
        for (int j = 0; j < 2; ++j) acc[i][j] = (float4v){0.f, 0.f, 0.f, 0.f};

    int sRow = wave * 32 + (lane >> 2);
    int sK = (lane & 3) * 8;
    int fr = lane & 15, fk = (lane >> 4) * 8;
    int bn = tid >> 3, bk4 = (tid & 7) * 4;

    for (int k0 = 0; k0 < 256; k0 += 32) {
        int r0 = rowBase + sRow;       if (r0 >= M) r0 = M - 1;
        int r1 = rowBase + sRow + 16;  if (r1 >= M) r1 = M - 1;
        __builtin_amdgcn_global_load_lds((const AS1 void*)(A + (size_t)r0 * 256 + k0 + sK),
                                         (AS3 void*)&Als[(wave * 32) * 32], 16, 0, 0);
        __builtin_amdgcn_global_load_lds((const AS1 void*)(A + (size_t)r1 * 256 + k0 + sK),
                                         (AS3 void*)&Als[(wave * 32 + 16) * 32], 16, 0, 0);
        // B tile: 32 n-rows x 32 k, plain LDS write
        *(ushort4*)&Bls[bn * 32 + bk4] = *(const ushort4*)&Wt2[bn * 256 + k0 + bk4];
        __syncthreads();

        short8 af[2], bfr[2];
#pragma unroll
        for (int i = 0; i < 2; ++i)
            af[i] = *(const short8*)&Als[(wave * 32 + i * 16 + fr) * 32 + fk];
#pragma unroll
        for (int j = 0; j < 2; ++j)
            bfr[j] = *(const short8*)&Bls[(j * 16 + fr) * 32 + fk];
#pragma unroll
        for (int i = 0; i < 2; ++i)
#pragma unroll
            for (int j = 0; j < 2; ++j)
                acc[i][j] = __builtin_amdgcn_mfma_f32_16x16x32_bf16(af[i], bfr[j], acc[i][j], 0, 0, 0);
        __syncthreads();
    }

    int cr = (lane >> 4) * 4, cc = lane & 15;
#pragma unroll
    for (int i = 0; i < 2; ++i) {
#pragma unroll
        for (int j = 0; j < 2; ++j) {
            int colg = j * 16 + cc;
            float bv = b2[colg];
#pragma unroll
            for (int r = 0; r < 4; ++r) {
                int rowg = rowBase + wave * 32 + i * 16 + cr + r;
                if (rowg < M) out[(size_t)rowg * 32 + colg] = acc[i][j][r] + bv;
            }
        }
    }
}

// ---------------------------------------------------------------------------
extern "C" void kernel_launch(void* const* d_in, const int* in_sizes, int n_in,
                              void* d_out, int out_size, void* d_ws, size_t ws_size,
                              hipStream_t stream) {
    const float* x   = (const float*)d_in[0];
    const int* edge  = (const int*)d_in[1];
    const float* W0  = (const float*)d_in[2];
    const float* b0  = (const float*)d_in[3];
    const float* Wn0 = (const float*)d_in[4];
    const float* bn0 = (const float*)d_in[5];
    const float* W1  = (const float*)d_in[6];
    const float* b1  = (const float*)d_in[7];
    const float* Wn1 = (const float*)d_in[8];
    const float* bn1 = (const float*)d_in[9];
    const float* W2  = (const float*)d_in[10];
    const float* b2  = (const float*)d_in[11];
    float* out = (float*)d_out;

    const int N = NN, E = NE;
    const int* row = edge;
    const int* col = edge + E;

    // Workspace layout
    char* p = (char*)d_ws;
    unsigned short* Xbf = (unsigned short*)p; p += (size_t)N * DD * 2;   // 25.6MB
    unsigned short* Abf = (unsigned short*)p; p += (size_t)N * DD * 2;
    unsigned short* Bbf = (unsigned short*)p; p += (size_t)N * DD * 2;
    unsigned short* Wt0  = (unsigned short*)p; p += 256 * 256 * 2;
    unsigned short* Wtn0 = (unsigned short*)p; p += 256 * 256 * 2;
    unsigned short* Wt1  = (unsigned short*)p; p += 256 * 256 * 2;
    unsigned short* Wtn1 = (unsigned short*)p; p += 256 * 256 * 2;
    unsigned short* Wt2  = (unsigned short*)p; p += 32 * 256 * 2;
    int* cnt     = (int*)p; p += (size_t)N * 4;
    int* row_ptr = (int*)p; p += (size_t)(N + 1) * 4;
    int* cursor  = (int*)p; p += (size_t)N * 4;
    float* dinv  = (float*)p; p += (size_t)N * 4;
    int* csr_col = (int*)p; p += (size_t)E * 4;
    int* bsum    = (int*)p; p += 256 * 4;
    int* bpre    = (int*)p; p += 256 * 4;

    const int nblk = (N + 255) / 256;  // 196
    const int eb = (E + 255) / 256;

    // CSR build (parallel scan)
    hipMemsetAsync(cnt, 0, (size_t)N * sizeof(int), stream);
    count_kernel<<<eb, 256, 0, stream>>>(row, cnt, E);
    block_sums<<<nblk, 256, 0, stream>>>(cnt, bsum, N);
    scan_bsums<<<1, 256, 0, stream>>>(bsum, bpre, nblk);
    fill_rowptr<<<nblk, 256, 0, stream>>>(cnt, bpre, row_ptr, cursor, dinv, N, E);
    scatter_kernel<<<eb, 256, 0, stream>>>(row, col, cursor, csr_col, E);

    // casts
    cast_x_kernel<<<(N * DD / 4 + 255) / 256, 256, 0, stream>>>(x, Xbf, N * DD / 4);
    cast_wt_kernel<<<256, 256, 0, stream>>>(W0, Wt0, 256);
    cast_wt_kernel<<<256, 256, 0, stream>>>(Wn0, Wtn0, 256);
    cast_wt_kernel<<<256, 256, 0, stream>>>(W1, Wt1, 256);
    cast_wt_kernel<<<256, 256, 0, stream>>>(Wn1, Wtn1, 256);
    cast_wt_kernel<<<32, 256, 0, stream>>>(W2, Wt2, 32);

    dim3 g((N + 127) / 128, 2);  // 391 x 2
    // Layer 1
    gemm_mfma<<<g, 256, 0, stream>>>(Xbf, Wt0, b0, Abf, N);
    gemm_mfma<<<g, 256, 0, stream>>>(Abf, Wtn0, bn0, Bbf, N);
    agg_norm_relu<<<N / 4, 256, 0, stream>>>(Abf, Bbf, dinv, row_ptr, csr_col, Abf);
    // Layer 2
    gemm_mfma<<<g, 256, 0, stream>>>(Abf, Wt1, b1, Bbf, N);
    gemm_mfma<<<g, 256, 0, stream>>>(Bbf, Wtn1, bn1, Xbf, N);
    agg_norm_relu<<<N / 4, 256, 0, stream>>>(Bbf, Xbf, dinv, row_ptr, csr_col, Bbf);
    // Final projection
    gemm_final_mfma<<<(N + 127) / 128, 256, 0, stream>>>(Bbf, Wt2, b2, out, N);
}

// Round 3
// 409.866 us; speedup vs baseline: 2.4645x; 1.1303x over previous
//
#include <hip/hip_runtime.h>
#include <hip/hip_bf16.h>

#define NN 50000
#define NE 800000
#define DD 256
#define OO 32

typedef __attribute__((ext_vector_type(8))) short short8;
typedef __attribute__((ext_vector_type(4))) float float4v;

#define AS1 __attribute__((address_space(1)))
#define AS3 __attribute__((address_space(3)))

__device__ __forceinline__ float b2f(unsigned short u) {
    union { unsigned int i; float f; } x;
    x.i = ((unsigned int)u) << 16;
    return x.f;
}
__device__ __forceinline__ unsigned short f2b(float f) {
    union { float f; unsigned int i; } x;
    x.f = f;
    unsigned int r = x.i + 0x7FFFu + ((x.i >> 16) & 1u);  // RNE
    return (unsigned short)(r >> 16);
}

// ---------------------------------------------------------------------------
// CSR build
// ---------------------------------------------------------------------------
__global__ void count_kernel(const int* __restrict__ row, int* __restrict__ cnt, int E) {
    int e = blockIdx.x * blockDim.x + threadIdx.x;
    if (e < E) atomicAdd(&cnt[row[e]], 1);
}

__global__ __launch_bounds__(256) void block_sums(const int* __restrict__ cnt,
                                                  int* __restrict__ bsum, int N) {
    __shared__ int s[256];
    int idx = blockIdx.x * 256 + threadIdx.x;
    s[threadIdx.x] = (idx < N) ? cnt[idx] : 0;
    __syncthreads();
    for (int o = 128; o > 0; o >>= 1) {
        if (threadIdx.x < o) s[threadIdx.x] += s[threadIdx.x + o];
        __syncthreads();
    }
    if (threadIdx.x == 0) bsum[blockIdx.x] = s[0];
}

__global__ __launch_bounds__(256) void scan_bsums(const int* __restrict__ bsum,
                                                  int* __restrict__ bpre, int nb) {
    __shared__ int s[256];
    int t = threadIdx.x;
    int v0 = (t < nb) ? bsum[t] : 0;
    s[t] = v0;
    __syncthreads();
    for (int o = 1; o < 256; o <<= 1) {
        int v = (t >= o) ? s[t - o] : 0;
        __syncthreads();
        s[t] += v;
        __syncthreads();
    }
    if (t < nb) bpre[t] = s[t] - v0;  // exclusive prefix
}

__global__ __launch_bounds__(256) void fill_rowptr(const int* __restrict__ cnt,
                                                   const int* __restrict__ bpre,
                                                   int* __restrict__ row_ptr,
                                                   int* __restrict__ cursor,
                                                   float* __restrict__ dinv, int N, int E) {
    __shared__ int s[256];
    int t = threadIdx.x;
    int idx = blockIdx.x * 256 + t;
    int c = (idx < N) ? cnt[idx] : 0;
    s[t] = c;
    __syncthreads();
    for (int o = 1; o < 256; o <<= 1) {
        int v = (t >= o) ? s[t - o] : 0;
        __syncthreads();
        s[t] += v;
        __syncthreads();
    }
    int excl = bpre[blockIdx.x] + s[t] - c;
    if (idx < N) {
        row_ptr[idx] = excl;
        cursor[idx] = excl;
        dinv[idx] = rsqrtf((float)(c + 1));  // +1 self-loop
    }
    if (idx == N) row_ptr[N] = E;
}

__global__ void scatter_kernel(const int* __restrict__ row, const int* __restrict__ col,
                               int* __restrict__ cursor, int* __restrict__ csr_col, int E) {
    int e = blockIdx.x * blockDim.x + threadIdx.x;
    if (e < E) {
        int p = atomicAdd(&cursor[row[e]], 1);
        csr_col[p] = col[e];
    }
}

// ---------------------------------------------------------------------------
// fp32 -> bf16 casts
// ---------------------------------------------------------------------------
__global__ __launch_bounds__(256) void cast_x_kernel(const float* __restrict__ x,
                                                     unsigned short* __restrict__ xb, int n4) {
    int i = blockIdx.x * 256 + threadIdx.x;
    if (i < n4) {
        float4 v = ((const float4*)x)[i];
        ushort4 o;
        o.x = f2b(v.x); o.y = f2b(v.y); o.z = f2b(v.z); o.w = f2b(v.w);
        ((ushort4*)xb)[i] = o;
    }
}

// All four 256x256 weights transposed+cast in one launch.
// Wt[n][k] = bf16(W[k][n]); grid (256, 4): y selects matrix, x = output row n.
__global__ __launch_bounds__(256) void cast_wt4_kernel(const float* __restrict__ Wa,
                                                       const float* __restrict__ Wb,
                                                       const float* __restrict__ Wc,
                                                       const float* __restrict__ Wd,
                                                       unsigned short* __restrict__ Ta,
                                                       unsigned short* __restrict__ Tb,
                                                       unsigned short* __restrict__ Tc,
                                                       unsigned short* __restrict__ Td) {
    const float* W;
    unsigned short* T;
    switch (blockIdx.y) {
        case 0: W = Wa; T = Ta; break;
        case 1: W = Wb; T = Tb; break;
        case 2: W = Wc; T = Tc; break;
        default: W = Wd; T = Td; break;
    }
    int n = blockIdx.x;
    int k = threadIdx.x;
    T[n * 256 + k] = f2b(W[k * 256 + n]);
}

__global__ __launch_bounds__(256) void cast_wt_kernel(const float* __restrict__ W,
                                                      unsigned short* __restrict__ Wt, int Ncol) {
    int n = blockIdx.x;
    int k = threadIdx.x;
    Wt[n * 256 + k] = f2b(W[k * Ncol + n]);
}

// ---------------------------------------------------------------------------
// bf16 MFMA GEMM: C[M x 256](bf16) = A[M x 256](bf16) @ Wt^T + bias(fp32).
// 128x128 tile, BK=32, global_load_lds staging; coalesced LDS-staged epilogue.
// ---------------------------------------------------------------------------
__global__ __launch_bounds__(256) void gemm_mfma(const unsigned short* __restrict__ A,
                                                 const unsigned short* __restrict__ Wt,
                                                 const float* __restrict__ bias,
                                                 unsigned short* __restrict__ C, int M) {
    __shared__ unsigned short smem[9216];  // Als 4096 | Bls 4096; epilogue reuses as Cls 128*72
    unsigned short* Als = smem;
    unsigned short* Bls = smem + 4096;
    unsigned short* Cls = smem;

    int tid = threadIdx.x;
    int lane = tid & 63, wave = tid >> 6;
    int rowBase = blockIdx.x * 128, colBase = blockIdx.y * 128;

    float4v acc[4][4];
#pragma unroll
    for (int i = 0; i < 4; ++i)
#pragma unroll
        for (int j = 0; j < 4; ++j) acc[i][j] = (float4v){0.f, 0.f, 0.f, 0.f};

    int wm = (wave & 1) * 64, wn = (wave >> 1) * 64;
    int sRow = wave * 32 + (lane >> 2);  // staging row within tile
    int sK = (lane & 3) * 8;             // ushort offset within 32-wide k row
    int fr = lane & 15, fk = (lane >> 4) * 8;

    for (int k0 = 0; k0 < 256; k0 += 32) {
        int r0 = rowBase + sRow;       if (r0 >= M) r0 = M - 1;
        int r1 = rowBase + sRow + 16;  if (r1 >= M) r1 = M - 1;
        __builtin_amdgcn_global_load_lds((const AS1 void*)(A + (size_t)r0 * 256 + k0 + sK),
                                         (AS3 void*)&Als[(wave * 32) * 32], 16, 0, 0);
        __builtin_amdgcn_global_load_lds((const AS1 void*)(A + (size_t)r1 * 256 + k0 + sK),
                                         (AS3 void*)&Als[(wave * 32 + 16) * 32], 16, 0, 0);
        __builtin_amdgcn_global_load_lds((const AS1 void*)(Wt + (size_t)(colBase + sRow) * 256 + k0 + sK),
                                         (AS3 void*)&Bls[(wave * 32) * 32], 16, 0, 0);
        __builtin_amdgcn_global_load_lds((const AS1 void*)(Wt + (size_t)(colBase + sRow + 16) * 256 + k0 + sK),
                                         (AS3 void*)&Bls[(wave * 32 + 16) * 32], 16, 0, 0);
        __syncthreads();

        short8 af[4], bfr[4];
#pragma unroll
        for (int i = 0; i < 4; ++i)
            af[i] = *(const short8*)&Als[(wm + i * 16 + fr) * 32 + fk];
#pragma unroll
        for (int j = 0; j < 4; ++j)
            bfr[j] = *(const short8*)&Bls[(wn + j * 16 + fr) * 32 + fk];
#pragma unroll
        for (int i = 0; i < 4; ++i)
#pragma unroll
            for (int j = 0; j < 4; ++j)
                acc[i][j] = __builtin_amdgcn_mfma_f32_16x16x32_bf16(af[i], bfr[j], acc[i][j], 0, 0, 0);
        __syncthreads();
    }

    // Epilogue: stage 128x64 halves into LDS (stride 72 = 144B, 16B-aligned),
    // then coalesced 16B/lane stores. C/D layout: col=lane&15, row=(lane>>4)*4+reg.
    int cr = (lane >> 4) * 4, cc = lane & 15;
    int myHalf = wave >> 1;  // which 64-col half this wave's tiles live in
#pragma unroll
    for (int jh = 0; jh < 2; ++jh) {
        if (myHalf == jh) {
#pragma unroll
            for (int j = 0; j < 4; ++j) {
                float bv = bias[colBase + jh * 64 + j * 16 + cc];
#pragma unroll
                for (int i = 0; i < 4; ++i) {
#pragma unroll
                    for (int r = 0; r < 4; ++r) {
                        Cls[(wm + i * 16 + cr + r) * 72 + j * 16 + cc] = f2b(acc[i][j][r] + bv);
                    }
                }
            }
        }
        __syncthreads();
#pragma unroll
        for (int c = 0; c < 4; ++c) {
            int chunk = c * 256 + tid;          // 1024 chunks of 16B
            int rw = chunk >> 3, off = (chunk & 7) * 8;
            int gr = rowBase + rw;
            if (gr < M) {
                short8 val = *(const short8*)&Cls[rw * 72 + off];
                *(short8*)&C[(size_t)gr * 256 + colBase + jh * 64 + off] = val;
            }
        }
        __syncthreads();
    }
}

// ---------------------------------------------------------------------------
// Fused APPNP agg + residual + L2-norm + ReLU. One WAVE per node.
// Lane handles 4 features (ushort4 = 8B gather). 4-wide unrolled gather loop
// (dc=0 padding lanes) to keep 4 independent loads in flight per wave.
// ---------------------------------------------------------------------------
__global__ __launch_bounds__(256) void agg_norm_relu(const unsigned short* __restrict__ h0,
                                                     const unsigned short* __restrict__ nb,
                                                     const float* __restrict__ dinv,
                                                     const int* __restrict__ row_ptr,
                                                     const int* __restrict__ csr_col,
                                                     unsigned short* __restrict__ outp) {
    int wave = threadIdx.x >> 6, lane = threadIdx.x & 63;
    int v = blockIdx.x * 4 + wave;
    float dv = dinv[v];
    int base = v * 256 + lane * 4;
    ushort4 nbu = *(const ushort4*)(nb + base);
    float nbv0 = b2f(nbu.x), nbv1 = b2f(nbu.y), nbv2 = b2f(nbu.z), nbv3 = b2f(nbu.w);
    float a0 = dv * nbv0, a1 = dv * nbv1, a2 = dv * nbv2, a3 = dv * nbv3;

    int s = row_ptr[v], e = row_ptr[v + 1];
    for (int b0 = s; b0 < e; b0 += 64) {
        int mm = e - b0;
        if (mm > 64) mm = 64;
        int c = 0;
        float dc = 0.f;
        if (lane < mm) { c = csr_col[b0 + lane]; dc = dinv[c]; }
        int mm4 = (mm + 3) & ~3;  // padded lanes have dc=0, c=0 (harmless hot gather)
        for (int j = 0; j < mm4; j += 4) {
            int c0 = __shfl(c, j), c1 = __shfl(c, j + 1);
            int c2 = __shfl(c, j + 2), c3 = __shfl(c, j + 3);
            float d0 = __shfl(dc, j), d1 = __shfl(dc, j + 1);
            float d2 = __shfl(dc, j + 2), d3 = __shfl(dc, j + 3);
            ushort4 u0 = *(const ushort4*)(nb + c0 * 256 + lane * 4);
            ushort4 u1 = *(const ushort4*)(nb + c1 * 256 + lane * 4);
            ushort4 u2 = *(const ushort4*)(nb + c2 * 256 + lane * 4);
            ushort4 u3 = *(const ushort4*)(nb + c3 * 256 + lane * 4);
            a0 = fmaf(d0, b2f(u0.x), a0); a1 = fmaf(d0, b2f(u0.y), a1);
            a2 = fmaf(d0, b2f(u0.z), a2); a3 = fmaf(d0, b2f(u0.w), a3);
            a0 = fmaf(d1, b2f(u1.x), a0); a1 = fmaf(d1, b2f(u1.y), a1);
            a2 = fmaf(d1, b2f(u1.z), a2); a3 = fmaf(d1, b2f(u1.w), a3);
            a0 = fmaf(d2, b2f(u2.x), a0); a1 = fmaf(d2, b2f(u2.y), a1);
            a2 = fmaf(d2, b2f(u2.z), a2); a3 = fmaf(d2, b2f(u2.w), a3);
            a0 = fmaf(d3, b2f(u3.x), a0); a1 = fmaf(d3, b2f(u3.y), a1);
            a2 = fmaf(d3, b2f(u3.z), a2); a3 = fmaf(d3, b2f(u3.w), a3);
        }
    }
    ushort4 hu = *(const ushort4*)(h0 + base);
    float v0 = b2f(hu.x) + 0.5f * dv * a0 + 0.5f * nbv0;
    float v1 = b2f(hu.y) + 0.5f * dv * a1 + 0.5f * nbv1;
    float v2 = b2f(hu.z) + 0.5f * dv * a2 + 0.5f * nbv2;
    float v3 = b2f(hu.w) + 0.5f * dv * a3 + 0.5f * nbv3;
    float ss = v0 * v0 + v1 * v1 + v2 * v2 + v3 * v3;
#pragma unroll
    for (int o = 32; o > 0; o >>= 1) ss += __shfl_xor(ss, o);
    float inv = 1.0f / fmaxf(sqrtf(ss), 1e-12f);
    ushort4 o;
    o.x = f2b(fmaxf(v0 * inv, 0.f));
    o.y = f2b(fmaxf(v1 * inv, 0.f));
    o.z = f2b(fmaxf(v2 * inv, 0.f));
    o.w = f2b(fmaxf(v3 * inv, 0.f));
    *(ushort4*)(outp + base) = o;
}

// ---------------------------------------------------------------------------
// Final projection (MFMA): out[M x 32](fp32) = A[M x 256](bf16) @ W2 + b2
// ---------------------------------------------------------------------------
__global__ __launch_bounds__(256) void gemm_final_mfma(const unsigned short* __restrict__ A,
                                                       const unsigned short* __restrict__ Wt2,
                                                       const float* __restrict__ b2,
                                                       float* __restrict__ out, int M) {
    __shared__ unsigned short Als[128 * 32];
    __shared__ unsigned short Bls[32 * 32];
    int tid = threadIdx.x;
    int lane = tid & 63, wave = tid >> 6;
    int rowBase = blockIdx.x * 128;

    float4v acc[2][2];
#pragma unroll
    for (int i = 0; i < 2; ++i)
#pragma unroll
        for (int j = 0; j < 2; ++j) acc[i][j] = (float4v){0.f, 0.f, 0.f, 0.f};

    int sRow = wave * 32 + (lane >> 2);
    int sK = (lane & 3) * 8;
    int fr = lane & 15, fk = (lane >> 4) * 8;
    int bn = tid >> 3, bk4 = (tid & 7) * 4;

    for (int k0 = 0; k0 < 256; k0 += 32) {
        int r0 = rowBase + sRow;       if (r0 >= M) r0 = M - 1;
        int r1 = rowBase + sRow + 16;  if (r1 >= M) r1 = M - 1;
        __builtin_amdgcn_global_load_lds((const AS1 void*)(A + (size_t)r0 * 256 + k0 + sK),
                                         (AS3 void*)&Als[(wave * 32) * 32], 16, 0, 0);
        __builtin_amdgcn_global_load_lds((const AS1 void*)(A + (size_t)r1 * 256 + k0 + sK),
                                         (AS3 void*)&Als[(wave * 32 + 16) * 32], 16, 0, 0);
        *(ushort4*)&Bls[bn * 32 + bk4] = *(const ushort4*)&Wt2[bn * 256 + k0 + bk4];
        __syncthreads();

        short8 af[2], bfr[2];
#pragma unroll
        for (int i = 0; i < 2; ++i)
            af[i] = *(const short8*)&Als[(wave * 32 + i * 16 + fr) * 32 + fk];
#pragma unroll
        for (int j = 0; j < 2; ++j)
            bfr[j] = *(const short8*)&Bls[(j * 16 + fr) * 32 + fk];
#pragma unroll
        for (int i = 0; i < 2; ++i)
#pragma unroll
            for (int j = 0; j < 2; ++j)
                acc[i][j] = __builtin_amdgcn_mfma_f32_16x16x32_bf16(af[i], bfr[j], acc[i][j], 0, 0, 0);
        __syncthreads();
    }

    int cr = (lane >> 4) * 4, cc = lane & 15;
#pragma unroll
    for (int i = 0; i < 2; ++i) {
#pragma unroll
        for (int j = 0; j < 2; ++j) {
            int colg = j * 16 + cc;
            float bv = b2[colg];
#pragma unroll
            for (int r = 0; r < 4; ++r) {
                int rowg = rowBase + wave * 32 + i * 16 + cr + r;
                if (rowg < M) out[(size_t)rowg * 32 + colg] = acc[i][j][r] + bv;
            }
        }
    }
}

// ---------------------------------------------------------------------------
extern "C" void kernel_launch(void* const* d_in, const int* in_sizes, int n_in,
                              void* d_out, int out_size, void* d_ws, size_t ws_size,
                              hipStream_t stream) {
    const float* x   = (const float*)d_in[0];
    const int* edge  = (const int*)d_in[1];
    const float* W0  = (const float*)d_in[2];
    const float* b0  = (const float*)d_in[3];
    const float* Wn0 = (const float*)d_in[4];
    const float* bn0 = (const float*)d_in[5];
    const float* W1  = (const float*)d_in[6];
    const float* b1  = (const float*)d_in[7];
    const float* Wn1 = (const float*)d_in[8];
    const float* bn1 = (const float*)d_in[9];
    const float* W2  = (const float*)d_in[10];
    const float* b2  = (const float*)d_in[11];
    float* out = (float*)d_out;

    const int N = NN, E = NE;
    const int* row = edge;
    const int* col = edge + E;

    // Workspace layout
    char* p = (char*)d_ws;
    unsigned short* Xbf = (unsigned short*)p; p += (size_t)N * DD * 2;
    unsigned short* Abf = (unsigned short*)p; p += (size_t)N * DD * 2;
    unsigned short* Bbf = (unsigned short*)p; p += (size_t)N * DD * 2;
    unsigned short* Wt0  = (unsigned short*)p; p += 256 * 256 * 2;
    unsigned short* Wtn0 = (unsigned short*)p; p += 256 * 256 * 2;
    unsigned short* Wt1  = (unsigned short*)p; p += 256 * 256 * 2;
    unsigned short* Wtn1 = (unsigned short*)p; p += 256 * 256 * 2;
    unsigned short* Wt2  = (unsigned short*)p; p += 32 * 256 * 2;
    int* cnt     = (int*)p; p += (size_t)N * 4;
    int* row_ptr = (int*)p; p += (size_t)(N + 1) * 4;
    int* cursor  = (int*)p; p += (size_t)N * 4;
    float* dinv  = (float*)p; p += (size_t)N * 4;
    int* csr_col = (int*)p; p += (size_t)E * 4;
    int* bsum    = (int*)p; p += 256 * 4;
    int* bpre    = (int*)p; p += 256 * 4;

    const int nblk = (N + 255) / 256;  // 196
    const int eb = (E + 255) / 256;

    // CSR build
    hipMemsetAsync(cnt, 0, (size_t)N * sizeof(int), stream);
    count_kernel<<<eb, 256, 0, stream>>>(row, cnt, E);
    block_sums<<<nblk, 256, 0, stream>>>(cnt, bsum, N);
    scan_bsums<<<1, 256, 0, stream>>>(bsum, bpre, nblk);
    fill_rowptr<<<nblk, 256, 0, stream>>>(cnt, bpre, row_ptr, cursor, dinv, N, E);
    scatter_kernel<<<eb, 256, 0, stream>>>(row, col, cursor, csr_col, E);

    // casts
    cast_x_kernel<<<(N * DD / 4 + 255) / 256, 256, 0, stream>>>(x, Xbf, N * DD / 4);
    cast_wt4_kernel<<<dim3(256, 4), 256, 0, stream>>>(W0, Wn0, W1, Wn1, Wt0, Wtn0, Wt1, Wtn1);
    cast_wt_kernel<<<32, 256, 0, stream>>>(W2, Wt2, 32);

    dim3 g((N + 127) / 128, 2);  // 391 x 2
    // Layer 1
    gemm_mfma<<<g, 256, 0, stream>>>(Xbf, Wt0, b0, Abf, N);
    gemm_mfma<<<g, 256, 0, stream>>>(Abf, Wtn0, bn0, Bbf, N);
    agg_norm_relu<<<N / 4, 256, 0, stream>>>(Abf, Bbf, dinv, row_ptr, csr_col, Abf);
    // Layer 2
    gemm_mfma<<<g, 256, 0, stream>>>(Abf, Wt1, b1, Bbf, N);
    gemm_mfma<<<g, 256, 0, stream>>>(Bbf, Wtn1, bn1, Xbf, N);
    agg_norm_relu<<<N / 4, 256, 0, stream>>>(Bbf, Xbf, dinv, row_ptr, csr_col, Bbf);
    // Final projection
    gemm_final_mfma<<<(N + 127) / 128, 256, 0, stream>>>(Bbf, Wt2, b2, out, N);
}